// Round 8
// baseline (5129.752 us; speedup 1.0000x reference)
//
#include <hip/hip_runtime.h>

// Dims fixed by the reference
#define LAY 2
#define BATCH 64
#define TMAX 512
#define DIM 256
#define AST 264    // LDS activation row stride (bytes, fp8)
#define CHUNK 16   // pipeline handoff granularity (timesteps)

typedef float floatx4 __attribute__((ext_vector_type(4)));
typedef __bf16 bf16x8 __attribute__((ext_vector_type(8)));
#define MFMA_FP8  __builtin_amdgcn_mfma_f32_16x16x32_fp8_fp8
#define MFMA_BF16 __builtin_amdgcn_mfma_f32_16x16x32_bf16

// LDS-only barrier: orders ds ops (lgkmcnt) without draining vmcnt.
#define BAR_LDS() asm volatile("s_waitcnt lgkmcnt(0)\n\ts_barrier" ::: "memory")

// d_ws layout (requires ws >= ~74 MB)
#define OFF_WPW 0x60000     // bf16 B-frag W-mats, 6 x 128 KB  (ends 0x120000)
#define OFF_FLG 0x150000    // flags: [0..3] projA, [4..7] scan0, [8..23] projB
#define OFF_XP  0x200000    // layer-0 X-projections fp8, 25.2 MB
#define OFF_HP  0x1C00000   // layer-1 input projections fp8, 25.2 MB
#define OFF_HN  0x3600000   // hn0 bf16 [b*512+t][256], 16.8 MB

__device__ __forceinline__ unsigned short f2bf(float f) {
    unsigned int u = __float_as_uint(f);
    unsigned int r = u + 0x7fffu + ((u >> 16) & 1u);  // RNE
    return (unsigned short)(r >> 16);
}
__device__ __forceinline__ unsigned int pk2(float a, float b) {
    return (unsigned int)__builtin_amdgcn_cvt_pk_fp8_f32(a, b, 0, false);  // OCP e4m3 x2
}
__device__ __forceinline__ unsigned char f2q(float a) { return (unsigned char)(pk2(a, a) & 0xff); }
__device__ __forceinline__ void unp4(unsigned int u, float* f) {
    auto lo = __builtin_amdgcn_cvt_pk_f32_fp8((int)u, false);
    auto hi = __builtin_amdgcn_cvt_pk_f32_fp8((int)u, true);
    f[0] = lo[0]; f[1] = lo[1]; f[2] = hi[0]; f[3] = hi[1];
}
// sigmoid via raw v_rcp_f32 (1 instr vs ~10-instr IEEE div sequence).
__device__ __forceinline__ float sigf(float x) {
    return __builtin_amdgcn_rcpf(1.f + __expf(-x));
}
// tanh(y) = 2*sigmoid(2y) - 1
__device__ __forceinline__ float tanhfast2y(float twoy) { return 2.f * sigf(twoy) - 1.f; }

// ---------------------------------------------------------------------------
// Weight prep (identical math). Zeroes 32 pipeline flags and d_out.
// ---------------------------------------------------------------------------
__global__ void prep_weights(const float* __restrict__ Wz, const float* __restrict__ Wr,
                             const float* __restrict__ Wh, const float* __restrict__ Uz,
                             const float* __restrict__ Ur, const float* __restrict__ Uh,
                             unsigned char* __restrict__ ws, float* __restrict__ out) {
    int T = blockIdx.x * 256 + threadIdx.x;  // 1536*256 = 393216
    if (T == 0) out[0] = 0.f;
    if (T < 32) ((int*)(ws + OFF_FLG))[T] = 0;   // pipeline flags (ws re-poisoned each call)
    if (T < 196608) {  // U-mats, fp8
        int e = T & 3, half = (T >> 2) & 1, lane = (T >> 3) & 63;
        int kp = (T >> 9) & 3, nt = (T >> 11) & 15, mu = T >> 15;
        int g = mu % 3, l = mu / 3;
        const float* s = (g == 0 ? Uz : g == 1 ? Ur : Uh) + l * 65536;
        int n  = nt * 16 + (lane & 15);
        int k0 = (2 * kp + half) * 32 + (lane >> 4) * 8 + 2 * e;
        float w0 = s[(k0 << 8) + n] * 8.f;        // x8: dodge e4m3 denormals
        float w1 = s[((k0 + 1) << 8) + n] * 8.f;  // undone by 0.125 post-acc
        int addr = ((mu * 16 + nt) * 4 + kp) * 1024 + lane * 16 + half * 8 + 2 * e;
        *(unsigned short*)(ws + addr) = (unsigned short)(pk2(w0, w1) & 0xffff);
    } else {           // W-mats, bf16
        int T2 = T - 196608;
        int e = T2 & 3, lane = (T2 >> 2) & 63;
        int kf = (T2 >> 8) & 7, nt = (T2 >> 11) & 15, mw = T2 >> 15;
        int g = mw % 3, l = mw / 3;
        const float* s = (g == 0 ? Wz : g == 1 ? Wr : Wh) + l * 65536;
        int n  = nt * 16 + (lane & 15);
        int k0 = kf * 32 + (lane >> 4) * 8 + 2 * e;
        unsigned int v = (unsigned int)f2bf(s[(k0 << 8) + n]) |
                         ((unsigned int)f2bf(s[((k0 + 1) << 8) + n]) << 16);
        int addr = ((mw * 16 + nt) * 8 + kf) * 1024 + lane * 16 + 4 * e;
        *(unsigned int*)(ws + OFF_WPW + addr) = v;
    }
}

// ---------------------------------------------------------------------------
// GRU scan body (R6 math, 16 waves x 1 col-tile). NWF>0: wait on MIN of NWF
// upstream flags per chunk. POST: publish pflag per CHUNK. Per-step barriers
// LDS-only (BAR_LDS); full __syncthreads only at WAIT/POST boundaries.
// ---------------------------------------------------------------------------
template <int SCORE, int NWF, int POST>
__device__ __forceinline__ void scan_body(
    const unsigned int* __restrict__ xp, const unsigned char* __restrict__ wpU,
    int lbase, int bg, unsigned short* __restrict__ hnout,
    const int* __restrict__ xlen, const float* __restrict__ xlab,
    const float* __restrict__ Wo, float* __restrict__ out,
    int* wflags, int* pflag,
    unsigned char (*s1q)[AST], unsigned char (*rsq)[AST], float (*s1o)[264],
    float* wo1s, int* s_rdy, int tmax)
{
    const int tid = threadIdx.x, wave = tid >> 6, lane = tid & 63;
    const int l15 = lane & 15, quad = lane >> 4;
    const int b0 = bg * 16;

    for (int i = tid; i < 16 * AST; i += 1024) ((unsigned char*)s1q)[i] = 0;
    if (SCORE && tid < DIM) wo1s[tid] = Wo[2 * tid + 1];
    const int lenr = xlen[b0 + l15];
    const float labr = SCORE ? xlab[b0 + l15] : 0.f;
    (void)lenr; (void)labr;

    const int nt = wave;
    const int colA = nt * 16 + l15, rowb = quad * 4;

    // register-resident U fragments for this wave's 16-col tile
    long uz[8], ur[8], uh[8];
    {
        const unsigned char* pz = wpU + (size_t)(((lbase + 0) * 16 + nt) * 4) * 1024 + lane * 16;
        const unsigned char* pr = wpU + (size_t)(((lbase + 1) * 16 + nt) * 4) * 1024 + lane * 16;
        const unsigned char* ph = wpU + (size_t)(((lbase + 2) * 16 + nt) * 4) * 1024 + lane * 16;
#pragma unroll
        for (int kf = 0; kf < 8; ++kf) {
            int o = (kf >> 1) * 1024 + (kf & 1) * 8;
            uz[kf] = *(const long*)(pz + o);
            ur[kf] = *(const long*)(pr + o);
            uh[kf] = *(const long*)(ph + o);
        }
    }
    float s1r[4] = {};
    float accl = 0.f;
    int ready = 0;
    __syncthreads();

    for (int t = 0; t < tmax; ++t) {
        if constexpr (NWF > 0) {
            if (t >= ready) {
                if (tid == 0) {
                    int vv, g = 0;
                    for (;;) {
                        vv = 1 << 30;
#pragma unroll
                        for (int q = 0; q < NWF; ++q) {
                            int m = __hip_atomic_load(wflags + q, __ATOMIC_RELAXED, __HIP_MEMORY_SCOPE_AGENT);
                            vv = m < vv ? m : vv;
                        }
                        if (vv > t || ++g > (1 << 19)) break;   // fail visibly, never hang
                        __builtin_amdgcn_s_sleep(2);
                    }
                    __threadfence();          // agent acquire before data reads
                    *s_rdy = vv > t ? vv : t + 1;
                }
                __syncthreads();
                ready = *s_rdy;
            }
        }

        const unsigned int* xpt = xp + (size_t)(bg * 512 + t) * 3072 + lane;
        unsigned int xz = xpt[nt * 64];
        unsigned int xr = xpt[1024 + nt * 64];
        unsigned int xh = xpt[2048 + nt * 64];

        // ---- phase 1: r (on the critical path) + z-MFMAs (acc dangles) ----
        long sf[8];
#pragma unroll
        for (int kf = 0; kf < 8; ++kf) sf[kf] = *(const long*)&s1q[l15][kf * 32 + quad * 8];
        floatx4 za = {0.f, 0.f, 0.f, 0.f}, ra = za;
#pragma unroll
        for (int kf = 0; kf < 8; ++kf) {
            ra = MFMA_FP8(sf[kf], ur[kf], ra, 0, 0, 0);
            za = MFMA_FP8(sf[kf], uz[kf], za, 0, 0, 0);
        }
        float xrf[4];
        unp4(xr, xrf);
#pragma unroll
        for (int i = 0; i < 4; ++i) {
            float r = sigf(0.125f * ra[i] + 0.0625f * xrf[i]);
            rsq[rowb + i][colA] = f2q(r * s1r[i]);
        }
        BAR_LDS();   // LDS-only: XP loads / HN stores stay in flight

        // ---- phase 2: h; z-sigmoid overlaps the Uh MFMA ----
        long rf[8];
#pragma unroll
        for (int kf = 0; kf < 8; ++kf) rf[kf] = *(const long*)&rsq[l15][kf * 32 + quad * 8];
        floatx4 ha = {0.f, 0.f, 0.f, 0.f};
#pragma unroll
        for (int kf = 0; kf < 8; ++kf) ha = MFMA_FP8(rf[kf], uh[kf], ha, 0, 0, 0);
        float xzf[4], xhf[4];
        unp4(xz, xzf); unp4(xh, xhf);
#pragma unroll
        for (int i = 0; i < 4; ++i) {
            float z = sigf(0.125f * za[i] + 0.0625f * xzf[i]);
            float h = tanhfast2y(0.25f * ha[i] + 0.125f * xhf[i]);  // tanh(0.125ha+0.0625xh)
            float hn = (1.f - z) * s1r[i] + z * h;
            s1r[i] = hn;
            s1q[rowb + i][colA] = f2q(hn);
            s1o[rowb + i][colA] = hn;
        }
        BAR_LDS();   // LDS-only

        if (!SCORE) {
            // cooperative hn0 write: row=tid>>6, 4 cols/thread; coalesced 8B stores
            const int r = tid >> 6, c = (tid & 63) * 4;
            float4 f0 = *(const float4*)&s1o[r][c];
            uint2 o2;
            o2.x = f2bf(f0.x) | ((unsigned)f2bf(f0.y) << 16);
            o2.y = f2bf(f0.z) | ((unsigned)f2bf(f0.w) << 16);
            *(uint2*)(hnout + ((size_t)(b0 + r) * 512 + t) * 256 + c) = o2;
        } else if (wave == 0) {
            const int row = l15, c0 = quad * 64;
            float p = 0.f;
#pragma unroll
            for (int u = 0; u < 64; u += 4) {
                float4 sv = *(const float4*)&s1o[row][c0 + u];
                float4 wv = *(const float4*)&wo1s[c0 + u];
                p = fmaf(sv.x, wv.x, p); p = fmaf(sv.y, wv.y, p);
                p = fmaf(sv.z, wv.z, p); p = fmaf(sv.w, wv.w, p);
            }
            p += __shfl_xor(p, 16);
            p += __shfl_xor(p, 32);
            if (lane < 16 && t < lenr) {
                float sc = sigf(p);
                float d = labr - sc;
                accl = fmaf(d, d, accl);
            }
        }

        if (POST && (((t & (CHUNK - 1)) == (CHUNK - 1)) || t == tmax - 1)) {
            __syncthreads();   // FULL drain: all waves' HN stores (vmcnt0) before fence
            if (tid == 0) {
                __threadfence();   // agent release: push chunk data to coherent point
                __hip_atomic_store(pflag, t + 1, __ATOMIC_RELEASE, __HIP_MEMORY_SCOPE_AGENT);
            }
        }
    }

    if (SCORE && wave == 0) {
        accl += __shfl_xor(accl, 1);
        accl += __shfl_xor(accl, 2);
        accl += __shfl_xor(accl, 4);
        accl += __shfl_xor(accl, 8);
        if (lane == 0) atomicAdd(out, accl);
    }
}

// ---------------------------------------------------------------------------
// Fused 4-stage pipeline, 28 WGs (R6 topology + projA folded in as 4 WGs):
//   blocks 0-3  : projA  XP[t] = x[t] @ W(l0); whole chunk per WG,
//                 posts flags[bg] per chunk (no upstream wait)
//   blocks 4-7  : layer-0 scan (waits flags[bg]; posts flags[4+bg])
//   blocks 8-23 : projB, 4 WGs per bg; WG p owns t in [base+4p, base+4p+4);
//                 waits flags[4+bg], posts flags[8+bg*4+p]
//   blocks 24-27: layer-1 scan + loss (waits MIN of the bg's 4 projB flags)
// Only 4 extra fence-posting WGs vs R6 (128 added wbl2s) — R3's failure mode
// (16 extra posting WGs, tripled WRITE_SIZE) is the thing we're avoiding.
// ---------------------------------------------------------------------------
__global__ __launch_bounds__(1024, 4) void fused_pipeline(
    const float* __restrict__ x,
    unsigned int* __restrict__ XP, unsigned int* __restrict__ HP,
    const unsigned char* __restrict__ wpU, const unsigned char* __restrict__ wpW,
    unsigned short* __restrict__ HN,
    const int* __restrict__ xlen, const float* __restrict__ xlab,
    const float* __restrict__ Wo, float* __restrict__ out, int* flags)
{
    __shared__ __align__(16) unsigned char s1q[16][AST];
    __shared__ __align__(16) unsigned char rsq[16][AST];
    __shared__ __align__(16) float s1o[16][264];
    __shared__ float wo1s[DIM];
    __shared__ int s_rdy;

    const int bid = blockIdx.x;
    int role, bg, p = 0;
    if (bid < 4)       { role = 0; bg = bid; }
    else if (bid < 8)  { role = 1; bg = bid - 4; }
    else if (bid < 24) { role = 2; bg = (bid - 8) >> 2; p = (bid - 8) & 3; }
    else               { role = 3; bg = bid - 24; }

    const int tid = threadIdx.x, wave = tid >> 6, lane = tid & 63;
    const int l15 = lane & 15, quad = lane >> 4;
    const int b0 = bg * 16;

    // uniform tmax = max xlen over this bg's 16 rows (same in all stages)
    int v = xlen[b0 + l15];
#pragma unroll
    for (int o = 1; o < 16; o <<= 1) v = max(v, __shfl_xor(v, o));
    const int tmax = __builtin_amdgcn_readfirstlane(v);

    if (role == 0) {
        // ---- projA: XP[t] = x[t] @ W(l0); one WG per bg, whole chunk ----
        int* pf = flags + bg;
        const unsigned char* bz = wpW + (size_t)((0 * 16 + wave) * 8) * 1024 + lane * 16;
        const unsigned char* br = wpW + (size_t)((1 * 16 + wave) * 8) * 1024 + lane * 16;
        const unsigned char* bh = wpW + (size_t)((2 * 16 + wave) * 8) * 1024 + lane * 16;
        for (int base = 0; base < tmax; base += CHUNK) {
            const int t1 = (base + CHUNK < tmax) ? base + CHUNK : tmax;
            for (int t = base; t < t1; ++t) {
                const float* s = x + ((size_t)(b0 + l15) * 512 + t) * 256;
                bf16x8 af[8];
#pragma unroll
                for (int kf = 0; kf < 8; ++kf) {
                    float4 a = *(const float4*)(s + kf * 32 + quad * 8);
                    float4 b = *(const float4*)(s + kf * 32 + quad * 8 + 4);
                    union { unsigned short u[8]; bf16x8 v; } cv;
                    cv.u[0] = f2bf(a.x); cv.u[1] = f2bf(a.y); cv.u[2] = f2bf(a.z); cv.u[3] = f2bf(a.w);
                    cv.u[4] = f2bf(b.x); cv.u[5] = f2bf(b.y); cv.u[6] = f2bf(b.z); cv.u[7] = f2bf(b.w);
                    af[kf] = cv.v;
                }
                floatx4 az = {0.f, 0.f, 0.f, 0.f}, ar = az, ah = az;
#pragma unroll
                for (int kf = 0; kf < 8; ++kf) {
                    az = MFMA_BF16(af[kf], *(const bf16x8*)(bz + kf * 1024), az, 0, 0, 0);
                    ar = MFMA_BF16(af[kf], *(const bf16x8*)(br + kf * 1024), ar, 0, 0, 0);
                    ah = MFMA_BF16(af[kf], *(const bf16x8*)(bh + kf * 1024), ah, 0, 0, 0);
                }
                const size_t ob = (size_t)(bg * 512 + t) * 3072 + wave * 64 + lane;
                XP[ob]        = pk2(16.f * az[0], 16.f * az[1]) | (pk2(16.f * az[2], 16.f * az[3]) << 16);
                XP[ob + 1024] = pk2(16.f * ar[0], 16.f * ar[1]) | (pk2(16.f * ar[2], 16.f * ar[3]) << 16);
                XP[ob + 2048] = pk2(16.f * ah[0], 16.f * ah[1]) | (pk2(16.f * ah[2], 16.f * ah[3]) << 16);
            }
            __syncthreads();   // all waves' XP stores drained (vmcnt0 before barrier)
            if (tid == 0) {
                __threadfence();   // release: push XP chunk to coherent point
                __hip_atomic_store(pf, base + CHUNK, __ATOMIC_RELEASE, __HIP_MEMORY_SCOPE_AGENT);
            }
        }
    } else if (role == 1) {
        scan_body<0, 1, 1>(XP, wpU, 0, bg, HN, xlen, xlab, Wo, out,
                           flags + bg, flags + 4 + bg, s1q, rsq, s1o, wo1s, &s_rdy, tmax);
    } else if (role == 3) {
        scan_body<1, 4, 0>(HP, wpU, 3, bg, nullptr, xlen, xlab, Wo, out,
                           flags + 8 + bg * 4, nullptr, s1q, rsq, s1o, wo1s, &s_rdy, tmax);
    } else {
        // ---- projB: HP[t] = HN[t] @ W(l1); this WG owns 4 t per chunk ----
        int* wf = flags + 4 + bg;
        int* pf = flags + 8 + bg * 4 + p;
        const unsigned char* bz = wpW + (size_t)(((3 + 0) * 16 + wave) * 8) * 1024 + lane * 16;
        const unsigned char* br = wpW + (size_t)(((3 + 1) * 16 + wave) * 8) * 1024 + lane * 16;
        const unsigned char* bh = wpW + (size_t)(((3 + 2) * 16 + wave) * 8) * 1024 + lane * 16;
        for (int base = 0; base < tmax; base += CHUNK) {
            const int target = (base + CHUNK < tmax) ? base + CHUNK : tmax;
            if (tid == 0) {
                int vv, g = 0;
                for (;;) {
                    vv = __hip_atomic_load(wf, __ATOMIC_RELAXED, __HIP_MEMORY_SCOPE_AGENT);
                    if (vv >= target || ++g > (1 << 19)) break;
                    __builtin_amdgcn_s_sleep(2);
                }
                __threadfence();   // acquire: see scan0's HN chunk
            }
            __syncthreads();       // no wave reads HN before the inv

            const int t0 = base + p * 4;
            const int t1 = (t0 + 4 < tmax) ? t0 + 4 : tmax;
            for (int t = t0; t < t1; ++t) {
                const unsigned short* sA = HN + ((size_t)(b0 + l15) * 512 + t) * 256;
                bf16x8 af[8];
#pragma unroll
                for (int kf = 0; kf < 8; ++kf) af[kf] = *(const bf16x8*)(sA + kf * 32 + quad * 8);
                floatx4 az = {0.f, 0.f, 0.f, 0.f}, ar = az, ah = az;
#pragma unroll
                for (int kf = 0; kf < 8; ++kf) {
                    az = MFMA_BF16(af[kf], *(const bf16x8*)(bz + kf * 1024), az, 0, 0, 0);
                    ar = MFMA_BF16(af[kf], *(const bf16x8*)(br + kf * 1024), ar, 0, 0, 0);
                    ah = MFMA_BF16(af[kf], *(const bf16x8*)(bh + kf * 1024), ah, 0, 0, 0);
                }
                const size_t ob = (size_t)(bg * 512 + t) * 3072 + wave * 64 + lane;
                HP[ob]        = pk2(16.f * az[0], 16.f * az[1]) | (pk2(16.f * az[2], 16.f * az[3]) << 16);
                HP[ob + 1024] = pk2(16.f * ar[0], 16.f * ar[1]) | (pk2(16.f * ar[2], 16.f * ar[3]) << 16);
                HP[ob + 2048] = pk2(16.f * ah[0], 16.f * ah[1]) | (pk2(16.f * ah[2], 16.f * ah[3]) << 16);
            }

            __syncthreads();   // all waves' HP stores drained (vmcnt0 before barrier)
            if (tid == 0) {
                __threadfence();   // release: push HP chunk to coherent point
                __hip_atomic_store(pf, base + CHUNK, __ATOMIC_RELEASE, __HIP_MEMORY_SCOPE_AGENT);
            }
        }
    }
}

extern "C" void kernel_launch(void* const* d_in, const int* in_sizes, int n_in,
                              void* d_out, int out_size, void* d_ws, size_t ws_size,
                              hipStream_t stream) {
    const float* x    = (const float*)d_in[0];
    const int*   xlen = (const int*)d_in[1];
    const float* xlab = (const float*)d_in[2];
    const float* Wz   = (const float*)d_in[3];
    const float* Uz   = (const float*)d_in[4];
    const float* Wr   = (const float*)d_in[5];
    const float* Ur   = (const float*)d_in[6];
    const float* Wh   = (const float*)d_in[7];
    const float* Uh   = (const float*)d_in[8];
    const float* Wo   = (const float*)d_in[9];
    float* out = (float*)d_out;

    unsigned char* ws  = (unsigned char*)d_ws;
    unsigned char* wpU = ws;                                 // fp8 U-frags, 384 KB
    unsigned char* wpW = ws + OFF_WPW;                       // bf16 W-frags, 768 KB
    int*           FLG = (int*)(ws + OFF_FLG);               // pipeline flags
    unsigned int*  XP  = (unsigned int*)(ws + OFF_XP);       // 25.2 MB
    unsigned int*  HP  = (unsigned int*)(ws + OFF_HP);       // 25.2 MB
    unsigned short* HN = (unsigned short*)(ws + OFF_HN);     // 16.8 MB

    // ws re-poisoned every call -> rebuild everything (incl. flags) each time.
    prep_weights<<<1536, 256, 0, stream>>>(Wz, Wr, Wh, Uz, Ur, Uh, ws, out);
    fused_pipeline<<<28, 1024, 0, stream>>>(x, XP, HP, wpU, wpW, HN,
                                            xlen, xlab, Wo, out, FLG);
}

// Round 9
// 1266.365 us; speedup vs baseline: 4.0508x; 4.0508x over previous
//
#include <hip/hip_runtime.h>

// Dims fixed by the reference
#define LAY 2
#define BATCH 64
#define TMAX 512
#define DIM 256
#define AST 264    // LDS activation row stride (bytes, fp8)
#define CHUNK 16   // pipeline handoff granularity (timesteps)

typedef float floatx4 __attribute__((ext_vector_type(4)));
typedef __bf16 bf16x8 __attribute__((ext_vector_type(8)));
#define MFMA_FP8  __builtin_amdgcn_mfma_f32_16x16x32_fp8_fp8
#define MFMA_BF16 __builtin_amdgcn_mfma_f32_16x16x32_bf16

// LDS-only barrier: orders ds ops (lgkmcnt) without draining vmcnt.
#define BAR_LDS() asm volatile("s_waitcnt lgkmcnt(0)\n\ts_barrier" ::: "memory")

// d_ws layout (requires ws >= ~74 MB)
#define OFF_WPW 0x60000     // bf16 B-frag W-mats, 6 x 128 KB  (ends 0x120000)
#define OFF_FLG 0x150000    // [0..3] scan0 flags, [4..19] projB flags,
                            // [32..159] projA chunk counters (bg*32+chunk)
#define OFF_XP  0x200000    // layer-0 X-projections fp8, 25.2 MB
#define OFF_HP  0x1C00000   // layer-1 input projections fp8, 25.2 MB
#define OFF_HN  0x3600000   // hn0 bf16 [b*512+t][256], 16.8 MB

__device__ __forceinline__ unsigned short f2bf(float f) {
    unsigned int u = __float_as_uint(f);
    unsigned int r = u + 0x7fffu + ((u >> 16) & 1u);  // RNE
    return (unsigned short)(r >> 16);
}
__device__ __forceinline__ unsigned int pk2(float a, float b) {
    return (unsigned int)__builtin_amdgcn_cvt_pk_fp8_f32(a, b, 0, false);  // OCP e4m3 x2
}
__device__ __forceinline__ unsigned char f2q(float a) { return (unsigned char)(pk2(a, a) & 0xff); }
__device__ __forceinline__ void unp4(unsigned int u, float* f) {
    auto lo = __builtin_amdgcn_cvt_pk_f32_fp8((int)u, false);
    auto hi = __builtin_amdgcn_cvt_pk_f32_fp8((int)u, true);
    f[0] = lo[0]; f[1] = lo[1]; f[2] = hi[0]; f[3] = hi[1];
}
// sigmoid via raw v_rcp_f32 (1 instr vs ~10-instr IEEE div sequence).
__device__ __forceinline__ float sigf(float x) {
    return __builtin_amdgcn_rcpf(1.f + __expf(-x));
}
// tanh(y) = 2*sigmoid(2y) - 1
__device__ __forceinline__ float tanhfast2y(float twoy) { return 2.f * sigf(twoy) - 1.f; }

// ---------------------------------------------------------------------------
// Weight prep (identical math). Zeroes flags+counters (192 ints) and d_out.
// ---------------------------------------------------------------------------
__global__ void prep_weights(const float* __restrict__ Wz, const float* __restrict__ Wr,
                             const float* __restrict__ Wh, const float* __restrict__ Uz,
                             const float* __restrict__ Ur, const float* __restrict__ Uh,
                             unsigned char* __restrict__ ws, float* __restrict__ out) {
    int T = blockIdx.x * 256 + threadIdx.x;  // 1536*256 = 393216
    if (T == 0) out[0] = 0.f;
    if (T < 192) ((int*)(ws + OFF_FLG))[T] = 0;  // flags + projA counters
    if (T < 196608) {  // U-mats, fp8
        int e = T & 3, half = (T >> 2) & 1, lane = (T >> 3) & 63;
        int kp = (T >> 9) & 3, nt = (T >> 11) & 15, mu = T >> 15;
        int g = mu % 3, l = mu / 3;
        const float* s = (g == 0 ? Uz : g == 1 ? Ur : Uh) + l * 65536;
        int n  = nt * 16 + (lane & 15);
        int k0 = (2 * kp + half) * 32 + (lane >> 4) * 8 + 2 * e;
        float w0 = s[(k0 << 8) + n] * 8.f;        // x8: dodge e4m3 denormals
        float w1 = s[((k0 + 1) << 8) + n] * 8.f;  // undone by 0.125 post-acc
        int addr = ((mu * 16 + nt) * 4 + kp) * 1024 + lane * 16 + half * 8 + 2 * e;
        *(unsigned short*)(ws + addr) = (unsigned short)(pk2(w0, w1) & 0xffff);
    } else {           // W-mats, bf16
        int T2 = T - 196608;
        int e = T2 & 3, lane = (T2 >> 2) & 63;
        int kf = (T2 >> 8) & 7, nt = (T2 >> 11) & 15, mw = T2 >> 15;
        int g = mw % 3, l = mw / 3;
        const float* s = (g == 0 ? Wz : g == 1 ? Wr : Wh) + l * 65536;
        int n  = nt * 16 + (lane & 15);
        int k0 = kf * 32 + (lane >> 4) * 8 + 2 * e;
        unsigned int v = (unsigned int)f2bf(s[(k0 << 8) + n]) |
                         ((unsigned int)f2bf(s[((k0 + 1) << 8) + n]) << 16);
        int addr = ((mw * 16 + nt) * 8 + kf) * 1024 + lane * 16 + 4 * e;
        *(unsigned int*)(ws + OFF_WPW + addr) = v;
    }
}

// ---------------------------------------------------------------------------
// GRU scan body (R6 math, 16 waves x 1 col-tile). WMODE: 0 = no wait,
// 1 = wait on MIN of 4 projB flags, 2 = wait on projA chunk counter == 16.
// POST: publish pflag per CHUNK. Per-step barriers LDS-only (BAR_LDS);
// full __syncthreads only at WAIT/POST chunk boundaries.
// ---------------------------------------------------------------------------
template <int SCORE, int WMODE, int POST>
__device__ __forceinline__ void scan_body(
    const unsigned int* __restrict__ xp, const unsigned char* __restrict__ wpU,
    int lbase, int bg, unsigned short* __restrict__ hnout,
    const int* __restrict__ xlen, const float* __restrict__ xlab,
    const float* __restrict__ Wo, float* __restrict__ out,
    int* wflags, int* pflag,
    unsigned char (*s1q)[AST], unsigned char (*rsq)[AST], float (*s1o)[264],
    float* wo1s, int* s_rdy, int tmax)
{
    const int tid = threadIdx.x, wave = tid >> 6, lane = tid & 63;
    const int l15 = lane & 15, quad = lane >> 4;
    const int b0 = bg * 16;

    for (int i = tid; i < 16 * AST; i += 1024) ((unsigned char*)s1q)[i] = 0;
    if (SCORE && tid < DIM) wo1s[tid] = Wo[2 * tid + 1];
    const int lenr = xlen[b0 + l15];
    const float labr = SCORE ? xlab[b0 + l15] : 0.f;
    (void)lenr; (void)labr;

    const int nt = wave;
    const int colA = nt * 16 + l15, rowb = quad * 4;

    // register-resident U fragments for this wave's 16-col tile
    long uz[8], ur[8], uh[8];
    {
        const unsigned char* pz = wpU + (size_t)(((lbase + 0) * 16 + nt) * 4) * 1024 + lane * 16;
        const unsigned char* pr = wpU + (size_t)(((lbase + 1) * 16 + nt) * 4) * 1024 + lane * 16;
        const unsigned char* ph = wpU + (size_t)(((lbase + 2) * 16 + nt) * 4) * 1024 + lane * 16;
#pragma unroll
        for (int kf = 0; kf < 8; ++kf) {
            int o = (kf >> 1) * 1024 + (kf & 1) * 8;
            uz[kf] = *(const long*)(pz + o);
            ur[kf] = *(const long*)(pr + o);
            uh[kf] = *(const long*)(ph + o);
        }
    }
    float s1r[4] = {};
    float accl = 0.f;
    int ready = 0;
    __syncthreads();

    for (int t = 0; t < tmax; ++t) {
        if constexpr (WMODE == 1) {
            if (t >= ready) {
                if (tid == 0) {
                    int vv, g = 0;
                    for (;;) {
                        vv = 1 << 30;
#pragma unroll
                        for (int q = 0; q < 4; ++q) {
                            int m = __hip_atomic_load(wflags + q, __ATOMIC_RELAXED, __HIP_MEMORY_SCOPE_AGENT);
                            vv = m < vv ? m : vv;
                        }
                        if (vv > t || ++g > (1 << 19)) break;   // fail visibly, never hang
                        __builtin_amdgcn_s_sleep(2);
                    }
                    __threadfence();          // agent acquire before data reads
                    *s_rdy = vv > t ? vv : t + 1;
                }
                __syncthreads();
                ready = *s_rdy;
            }
        } else if constexpr (WMODE == 2) {
            if (t >= ready) {
                if (tid == 0) {
                    const int ch = t >> 4;    // CHUNK == 16
                    int g = 0;
                    for (;;) {
                        int c = __hip_atomic_load(wflags + ch, __ATOMIC_RELAXED, __HIP_MEMORY_SCOPE_AGENT);
                        if (c >= 16 || ++g > (1 << 19)) break;  // fail visibly, never hang
                        __builtin_amdgcn_s_sleep(2);
                    }
                    __threadfence();          // agent acquire: inv before XP reads
                    *s_rdy = (ch + 1) * CHUNK;
                }
                __syncthreads();
                ready = *s_rdy;
            }
        }

        const unsigned int* xpt = xp + (size_t)(bg * 512 + t) * 3072 + lane;
        unsigned int xz = xpt[nt * 64];
        unsigned int xr = xpt[1024 + nt * 64];
        unsigned int xh = xpt[2048 + nt * 64];

        // ---- phase 1: r (on the critical path) + z-MFMAs (acc dangles) ----
        long sf[8];
#pragma unroll
        for (int kf = 0; kf < 8; ++kf) sf[kf] = *(const long*)&s1q[l15][kf * 32 + quad * 8];
        floatx4 za = {0.f, 0.f, 0.f, 0.f}, ra = za;
#pragma unroll
        for (int kf = 0; kf < 8; ++kf) {
            ra = MFMA_FP8(sf[kf], ur[kf], ra, 0, 0, 0);
            za = MFMA_FP8(sf[kf], uz[kf], za, 0, 0, 0);
        }
        float xrf[4];
        unp4(xr, xrf);
#pragma unroll
        for (int i = 0; i < 4; ++i) {
            float r = sigf(0.125f * ra[i] + 0.0625f * xrf[i]);
            rsq[rowb + i][colA] = f2q(r * s1r[i]);
        }
        BAR_LDS();   // LDS-only: XP loads / HN stores stay in flight

        // ---- phase 2: h; z-sigmoid overlaps the Uh MFMA ----
        long rf[8];
#pragma unroll
        for (int kf = 0; kf < 8; ++kf) rf[kf] = *(const long*)&rsq[l15][kf * 32 + quad * 8];
        floatx4 ha = {0.f, 0.f, 0.f, 0.f};
#pragma unroll
        for (int kf = 0; kf < 8; ++kf) ha = MFMA_FP8(rf[kf], uh[kf], ha, 0, 0, 0);
        float xzf[4], xhf[4];
        unp4(xz, xzf); unp4(xh, xhf);
#pragma unroll
        for (int i = 0; i < 4; ++i) {
            float z = sigf(0.125f * za[i] + 0.0625f * xzf[i]);
            float h = tanhfast2y(0.25f * ha[i] + 0.125f * xhf[i]);  // tanh(0.125ha+0.0625xh)
            float hn = (1.f - z) * s1r[i] + z * h;
            s1r[i] = hn;
            s1q[rowb + i][colA] = f2q(hn);
            s1o[rowb + i][colA] = hn;
        }
        BAR_LDS();   // LDS-only

        if (!SCORE) {
            // cooperative hn0 write: row=tid>>6, 4 cols/thread; coalesced 8B stores
            const int r = tid >> 6, c = (tid & 63) * 4;
            float4 f0 = *(const float4*)&s1o[r][c];
            uint2 o2;
            o2.x = f2bf(f0.x) | ((unsigned)f2bf(f0.y) << 16);
            o2.y = f2bf(f0.z) | ((unsigned)f2bf(f0.w) << 16);
            *(uint2*)(hnout + ((size_t)(b0 + r) * 512 + t) * 256 + c) = o2;
        } else if (wave == 0) {
            const int row = l15, c0 = quad * 64;
            float p = 0.f;
#pragma unroll
            for (int u = 0; u < 64; u += 4) {
                float4 sv = *(const float4*)&s1o[row][c0 + u];
                float4 wv = *(const float4*)&wo1s[c0 + u];
                p = fmaf(sv.x, wv.x, p); p = fmaf(sv.y, wv.y, p);
                p = fmaf(sv.z, wv.z, p); p = fmaf(sv.w, wv.w, p);
            }
            p += __shfl_xor(p, 16);
            p += __shfl_xor(p, 32);
            if (lane < 16 && t < lenr) {
                float sc = sigf(p);
                float d = labr - sc;
                accl = fmaf(d, d, accl);
            }
        }

        if (POST && (((t & (CHUNK - 1)) == (CHUNK - 1)) || t == tmax - 1)) {
            __syncthreads();   // FULL drain: all waves' HN stores (vmcnt0) before fence
            if (tid == 0) {
                __threadfence();   // agent release: push chunk data to coherent point
                __hip_atomic_store(pflag, t + 1, __ATOMIC_RELEASE, __HIP_MEMORY_SCOPE_AGENT);
            }
        }
    }

    if (SCORE && wave == 0) {
        accl += __shfl_xor(accl, 1);
        accl += __shfl_xor(accl, 2);
        accl += __shfl_xor(accl, 4);
        accl += __shfl_xor(accl, 8);
        if (lane == 0) atomicAdd(out, accl);
    }
}

// ---------------------------------------------------------------------------
// Fused pipeline + in-grid projA, 2072 WGs:
//   blocks 0-3   : layer-0 scan (waits projA counter==16 per chunk;
//                  posts flags[bg] per chunk)
//   blocks 4-19  : projB, 4 WGs per bg; waits flags[bg], posts flags[4+bg*4+p]
//   blocks 20-23 : layer-1 scan + loss (waits MIN of the bg's 4 projB flags)
//   blocks 24-2071: projA, one (bg,t) each (full 2048-block parallelism, the
//                  R6-standalone structure). XP stored via agent-scope relaxed
//                  atomics (device-coherent at LLC -> NO producer wbl2, the
//                  R3 failure mode); __syncthreads drains vmcnt, then one
//                  relaxed agent fetch_add on cnt[bg*32+chunk]. Consumer's
//                  acquire threadfence (inv) makes the data visible.
// Dispatch order is a perf heuristic only: producers are independent, so any
// schedule completes; consumer spins have fail-visible guards.
// ---------------------------------------------------------------------------
__global__ __launch_bounds__(1024, 4) void fused_pipeline(
    const float* __restrict__ x,
    unsigned int* __restrict__ XP, unsigned int* __restrict__ HP,
    const unsigned char* __restrict__ wpU, const unsigned char* __restrict__ wpW,
    unsigned short* __restrict__ HN,
    const int* __restrict__ xlen, const float* __restrict__ xlab,
    const float* __restrict__ Wo, float* __restrict__ out, int* flags)
{
    __shared__ __align__(16) unsigned char s1q[16][AST];
    __shared__ __align__(16) unsigned char rsq[16][AST];
    __shared__ __align__(16) float s1o[16][264];
    __shared__ float wo1s[DIM];
    __shared__ int s_rdy;

    const int bid = blockIdx.x;
    const int tid = threadIdx.x, wave = tid >> 6, lane = tid & 63;
    const int l15 = lane & 15, quad = lane >> 4;
    int* cnt = flags + 32;   // projA chunk counters, bg*32+chunk

    if (bid >= 24) {
        // ---- projA: XP[t] = x[t] @ W(l0); one (bg,t) per block ----
        const int idx = bid - 24;            // 0..2047
        const int pt = idx & 511, pbg = idx >> 9;
        const float* s = x + ((size_t)(pbg * 16 + l15) * 512 + pt) * 256;
        bf16x8 af[8];
#pragma unroll
        for (int kf = 0; kf < 8; ++kf) {
            float4 a = *(const float4*)(s + kf * 32 + quad * 8);
            float4 b = *(const float4*)(s + kf * 32 + quad * 8 + 4);
            union { unsigned short u[8]; bf16x8 v; } cv;
            cv.u[0] = f2bf(a.x); cv.u[1] = f2bf(a.y); cv.u[2] = f2bf(a.z); cv.u[3] = f2bf(a.w);
            cv.u[4] = f2bf(b.x); cv.u[5] = f2bf(b.y); cv.u[6] = f2bf(b.z); cv.u[7] = f2bf(b.w);
            af[kf] = cv.v;
        }
        floatx4 az = {0.f, 0.f, 0.f, 0.f}, ar = az, ah = az;
        const unsigned char* bz = wpW + (size_t)((0 * 16 + wave) * 8) * 1024 + lane * 16;
        const unsigned char* br = wpW + (size_t)((1 * 16 + wave) * 8) * 1024 + lane * 16;
        const unsigned char* bh = wpW + (size_t)((2 * 16 + wave) * 8) * 1024 + lane * 16;
#pragma unroll
        for (int kf = 0; kf < 8; ++kf) {
            az = MFMA_BF16(af[kf], *(const bf16x8*)(bz + kf * 1024), az, 0, 0, 0);
            ar = MFMA_BF16(af[kf], *(const bf16x8*)(br + kf * 1024), ar, 0, 0, 0);
            ah = MFMA_BF16(af[kf], *(const bf16x8*)(bh + kf * 1024), ah, 0, 0, 0);
        }
        const size_t ob = (size_t)(pbg * 512 + pt) * 3072 + wave * 64 + lane;
        unsigned int v0 = pk2(16.f * az[0], 16.f * az[1]) | (pk2(16.f * az[2], 16.f * az[3]) << 16);
        unsigned int v1 = pk2(16.f * ar[0], 16.f * ar[1]) | (pk2(16.f * ar[2], 16.f * ar[3]) << 16);
        unsigned int v2 = pk2(16.f * ah[0], 16.f * ah[1]) | (pk2(16.f * ah[2], 16.f * ah[3]) << 16);
        // agent-scope stores: device-coherent (bypass/through local L2)
        __hip_atomic_store(&XP[ob],        v0, __ATOMIC_RELAXED, __HIP_MEMORY_SCOPE_AGENT);
        __hip_atomic_store(&XP[ob + 1024], v1, __ATOMIC_RELAXED, __HIP_MEMORY_SCOPE_AGENT);
        __hip_atomic_store(&XP[ob + 2048], v2, __ATOMIC_RELAXED, __HIP_MEMORY_SCOPE_AGENT);
        __syncthreads();   // vmcnt(0): all block's coherent stores complete
        if (tid == 0)
            __hip_atomic_fetch_add(cnt + pbg * 32 + (pt >> 4), 1,
                                   __ATOMIC_RELAXED, __HIP_MEMORY_SCOPE_AGENT);
        return;
    }

    int role, bg, p = 0;
    if (bid < 4)       { role = 0; bg = bid; }
    else if (bid < 20) { role = 1; bg = (bid - 4) >> 2; p = (bid - 4) & 3; }
    else               { role = 2; bg = bid - 20; }
    const int b0 = bg * 16;

    // uniform tmax = max xlen over this bg's 16 rows (same in all stages)
    int v = xlen[b0 + l15];
#pragma unroll
    for (int o = 1; o < 16; o <<= 1) v = max(v, __shfl_xor(v, o));
    const int tmax = __builtin_amdgcn_readfirstlane(v);

    if (role == 0) {
        scan_body<0, 2, 1>(XP, wpU, 0, bg, HN, xlen, xlab, Wo, out,
                           cnt + bg * 32, flags + bg, s1q, rsq, s1o, wo1s, &s_rdy, tmax);
    } else if (role == 2) {
        scan_body<1, 1, 0>(HP, wpU, 3, bg, nullptr, xlen, xlab, Wo, out,
                           flags + 4 + bg * 4, nullptr, s1q, rsq, s1o, wo1s, &s_rdy, tmax);
    } else {
        // ---- projB: HP[t] = HN[t] @ W(l1); this WG owns 4 t per chunk ----
        int* wf = flags + bg;
        int* pf = flags + 4 + bg * 4 + p;
        const unsigned char* bz = wpW + (size_t)(((3 + 0) * 16 + wave) * 8) * 1024 + lane * 16;
        const unsigned char* br = wpW + (size_t)(((3 + 1) * 16 + wave) * 8) * 1024 + lane * 16;
        const unsigned char* bh = wpW + (size_t)(((3 + 2) * 16 + wave) * 8) * 1024 + lane * 16;
        for (int base = 0; base < tmax; base += CHUNK) {
            const int target = (base + CHUNK < tmax) ? base + CHUNK : tmax;
            if (tid == 0) {
                int vv, g = 0;
                for (;;) {
                    vv = __hip_atomic_load(wf, __ATOMIC_RELAXED, __HIP_MEMORY_SCOPE_AGENT);
                    if (vv >= target || ++g > (1 << 19)) break;
                    __builtin_amdgcn_s_sleep(2);
                }
                __threadfence();   // acquire: see scan0's HN chunk
            }
            __syncthreads();       // no wave reads HN before the inv

            const int t0 = base + p * 4;
            const int t1 = (t0 + 4 < tmax) ? t0 + 4 : tmax;
            for (int t = t0; t < t1; ++t) {
                const unsigned short* sA = HN + ((size_t)(b0 + l15) * 512 + t) * 256;
                bf16x8 af[8];
#pragma unroll
                for (int kf = 0; kf < 8; ++kf) af[kf] = *(const bf16x8*)(sA + kf * 32 + quad * 8);
                floatx4 az = {0.f, 0.f, 0.f, 0.f}, ar = az, ah = az;
#pragma unroll
                for (int kf = 0; kf < 8; ++kf) {
                    az = MFMA_BF16(af[kf], *(const bf16x8*)(bz + kf * 1024), az, 0, 0, 0);
                    ar = MFMA_BF16(af[kf], *(const bf16x8*)(br + kf * 1024), ar, 0, 0, 0);
                    ah = MFMA_BF16(af[kf], *(const bf16x8*)(bh + kf * 1024), ah, 0, 0, 0);
                }
                const size_t ob = (size_t)(bg * 512 + t) * 3072 + wave * 64 + lane;
                HP[ob]        = pk2(16.f * az[0], 16.f * az[1]) | (pk2(16.f * az[2], 16.f * az[3]) << 16);
                HP[ob + 1024] = pk2(16.f * ar[0], 16.f * ar[1]) | (pk2(16.f * ar[2], 16.f * ar[3]) << 16);
                HP[ob + 2048] = pk2(16.f * ah[0], 16.f * ah[1]) | (pk2(16.f * ah[2], 16.f * ah[3]) << 16);
            }

            __syncthreads();   // all waves' HP stores drained (vmcnt0 before barrier)
            if (tid == 0) {
                __threadfence();   // release: push HP chunk to coherent point
                __hip_atomic_store(pf, base + CHUNK, __ATOMIC_RELEASE, __HIP_MEMORY_SCOPE_AGENT);
            }
        }
    }
}

extern "C" void kernel_launch(void* const* d_in, const int* in_sizes, int n_in,
                              void* d_out, int out_size, void* d_ws, size_t ws_size,
                              hipStream_t stream) {
    const float* x    = (const float*)d_in[0];
    const int*   xlen = (const int*)d_in[1];
    const float* xlab = (const float*)d_in[2];
    const float* Wz   = (const float*)d_in[3];
    const float* Uz   = (const float*)d_in[4];
    const float* Wr   = (const float*)d_in[5];
    const float* Ur   = (const float*)d_in[6];
    const float* Wh   = (const float*)d_in[7];
    const float* Uh   = (const float*)d_in[8];
    const float* Wo   = (const float*)d_in[9];
    float* out = (float*)d_out;

    unsigned char* ws  = (unsigned char*)d_ws;
    unsigned char* wpU = ws;                                 // fp8 U-frags, 384 KB
    unsigned char* wpW = ws + OFF_WPW;                       // bf16 W-frags, 768 KB
    int*           FLG = (int*)(ws + OFF_FLG);               // flags + counters
    unsigned int*  XP  = (unsigned int*)(ws + OFF_XP);       // 25.2 MB
    unsigned int*  HP  = (unsigned int*)(ws + OFF_HP);       // 25.2 MB
    unsigned short* HN = (unsigned short*)(ws + OFF_HN);     // 16.8 MB

    // ws re-poisoned every call -> rebuild everything (incl. flags) each time.
    prep_weights<<<1536, 256, 0, stream>>>(Wz, Wr, Wh, Uz, Ur, Uh, ws, out);
    fused_pipeline<<<2072, 1024, 0, stream>>>(x, XP, HP, wpU, wpW, HN,
                                              xlen, xlab, Wo, out, FLG);
}

// Round 10
// 1262.044 us; speedup vs baseline: 4.0646x; 1.0034x over previous
//
#include <hip/hip_runtime.h>

// Dims fixed by the reference
#define LAY 2
#define BATCH 64
#define TMAX 512
#define DIM 256
#define AST 264    // LDS activation row stride (bytes, fp8)
#define CHUNK 16   // pipeline handoff granularity (timesteps)

typedef float floatx4 __attribute__((ext_vector_type(4)));
typedef __bf16 bf16x8 __attribute__((ext_vector_type(8)));
#define MFMA_FP8  __builtin_amdgcn_mfma_f32_16x16x32_fp8_fp8
#define MFMA_BF16 __builtin_amdgcn_mfma_f32_16x16x32_bf16

// LDS-only barrier: orders ds ops (lgkmcnt) without draining vmcnt.
#define BAR_LDS() asm volatile("s_waitcnt lgkmcnt(0)\n\ts_barrier" ::: "memory")

// d_ws layout (requires ws >= ~74 MB)
#define OFF_WPW 0x60000     // bf16 B-frag W-mats, 6 x 128 KB  (ends 0x120000)
#define OFF_FLG 0x150000    // [0..3] scan0 flags, [4..19] projB flags,
                            // [32..159] projA chunk counters (bg*32+chunk)
#define OFF_XP  0x200000    // layer-0 X-projections fp8, 25.2 MB
#define OFF_HP  0x1C00000   // layer-1 input projections fp8, 25.2 MB
#define OFF_HN  0x3600000   // hn0 bf16 [b*512+t][256], 16.8 MB

__device__ __forceinline__ unsigned short f2bf(float f) {
    unsigned int u = __float_as_uint(f);
    unsigned int r = u + 0x7fffu + ((u >> 16) & 1u);  // RNE
    return (unsigned short)(r >> 16);
}
__device__ __forceinline__ unsigned int pk2(float a, float b) {
    return (unsigned int)__builtin_amdgcn_cvt_pk_fp8_f32(a, b, 0, false);  // OCP e4m3 x2
}
__device__ __forceinline__ unsigned char f2q(float a) { return (unsigned char)(pk2(a, a) & 0xff); }
__device__ __forceinline__ void unp4(unsigned int u, float* f) {
    auto lo = __builtin_amdgcn_cvt_pk_f32_fp8((int)u, false);
    auto hi = __builtin_amdgcn_cvt_pk_f32_fp8((int)u, true);
    f[0] = lo[0]; f[1] = lo[1]; f[2] = hi[0]; f[3] = hi[1];
}
// sigmoid via raw v_rcp_f32 (1 instr vs ~10-instr IEEE div sequence).
__device__ __forceinline__ float sigf(float x) {
    return __builtin_amdgcn_rcpf(1.f + __expf(-x));
}
// tanh(y) = 2*sigmoid(2y) - 1
__device__ __forceinline__ float tanhfast2y(float twoy) { return 2.f * sigf(twoy) - 1.f; }

// agent-scope relaxed store/load: device-coherent at the LLC, no wbl2 needed
__device__ __forceinline__ void ast_u32(unsigned int* p, unsigned int v) {
    __hip_atomic_store(p, v, __ATOMIC_RELAXED, __HIP_MEMORY_SCOPE_AGENT);
}

// ---------------------------------------------------------------------------
// Weight prep (identical math). Zeroes flags+counters (192 ints) and d_out.
// ---------------------------------------------------------------------------
__global__ void prep_weights(const float* __restrict__ Wz, const float* __restrict__ Wr,
                             const float* __restrict__ Wh, const float* __restrict__ Uz,
                             const float* __restrict__ Ur, const float* __restrict__ Uh,
                             unsigned char* __restrict__ ws, float* __restrict__ out) {
    int T = blockIdx.x * 256 + threadIdx.x;  // 1536*256 = 393216
    if (T == 0) out[0] = 0.f;
    if (T < 192) ((int*)(ws + OFF_FLG))[T] = 0;  // flags + projA counters
    if (T < 196608) {  // U-mats, fp8
        int e = T & 3, half = (T >> 2) & 1, lane = (T >> 3) & 63;
        int kp = (T >> 9) & 3, nt = (T >> 11) & 15, mu = T >> 15;
        int g = mu % 3, l = mu / 3;
        const float* s = (g == 0 ? Uz : g == 1 ? Ur : Uh) + l * 65536;
        int n  = nt * 16 + (lane & 15);
        int k0 = (2 * kp + half) * 32 + (lane >> 4) * 8 + 2 * e;
        float w0 = s[(k0 << 8) + n] * 8.f;        // x8: dodge e4m3 denormals
        float w1 = s[((k0 + 1) << 8) + n] * 8.f;  // undone by 0.125 post-acc
        int addr = ((mu * 16 + nt) * 4 + kp) * 1024 + lane * 16 + half * 8 + 2 * e;
        *(unsigned short*)(ws + addr) = (unsigned short)(pk2(w0, w1) & 0xffff);
    } else {           // W-mats, bf16
        int T2 = T - 196608;
        int e = T2 & 3, lane = (T2 >> 2) & 63;
        int kf = (T2 >> 8) & 7, nt = (T2 >> 11) & 15, mw = T2 >> 15;
        int g = mw % 3, l = mw / 3;
        const float* s = (g == 0 ? Wz : g == 1 ? Wr : Wh) + l * 65536;
        int n  = nt * 16 + (lane & 15);
        int k0 = kf * 32 + (lane >> 4) * 8 + 2 * e;
        unsigned int v = (unsigned int)f2bf(s[(k0 << 8) + n]) |
                         ((unsigned int)f2bf(s[((k0 + 1) << 8) + n]) << 16);
        int addr = ((mw * 16 + nt) * 8 + kf) * 1024 + lane * 16 + 4 * e;
        *(unsigned int*)(ws + OFF_WPW + addr) = v;
    }
}

// ---------------------------------------------------------------------------
// GRU scan body (R6 math, 16 waves x 1 col-tile). WMODE: 0 = no wait,
// 1 = wait on MIN of 4 projB flags, 2 = wait on projA chunk counter == 16.
// POST: publish pflag per CHUNK via the R9 cheap-producer protocol:
// HN data goes out as agent-scope relaxed stores (coherent at LLC), the
// __syncthreads drains vmcnt, then a relaxed agent flag store — NO wbl2.
// Consumers' acquire __threadfence (inv) makes the data visible.
// Scan waves run at s_setprio(1): they are the global rate limiter and must
// win SIMD arbitration against co-resident projA/projB waves.
// ---------------------------------------------------------------------------
template <int SCORE, int WMODE, int POST>
__device__ __forceinline__ void scan_body(
    const unsigned int* __restrict__ xp, const unsigned char* __restrict__ wpU,
    int lbase, int bg, unsigned short* __restrict__ hnout,
    const int* __restrict__ xlen, const float* __restrict__ xlab,
    const float* __restrict__ Wo, float* __restrict__ out,
    int* wflags, int* pflag,
    unsigned char (*s1q)[AST], unsigned char (*rsq)[AST], float (*s1o)[264],
    float* wo1s, int* s_rdy, int tmax)
{
    const int tid = threadIdx.x, wave = tid >> 6, lane = tid & 63;
    const int l15 = lane & 15, quad = lane >> 4;
    const int b0 = bg * 16;

    for (int i = tid; i < 16 * AST; i += 1024) ((unsigned char*)s1q)[i] = 0;
    if (SCORE && tid < DIM) wo1s[tid] = Wo[2 * tid + 1];
    const int lenr = xlen[b0 + l15];
    const float labr = SCORE ? xlab[b0 + l15] : 0.f;
    (void)lenr; (void)labr;

    const int nt = wave;
    const int colA = nt * 16 + l15, rowb = quad * 4;

    // register-resident U fragments for this wave's 16-col tile
    long uz[8], ur[8], uh[8];
    {
        const unsigned char* pz = wpU + (size_t)(((lbase + 0) * 16 + nt) * 4) * 1024 + lane * 16;
        const unsigned char* pr = wpU + (size_t)(((lbase + 1) * 16 + nt) * 4) * 1024 + lane * 16;
        const unsigned char* ph = wpU + (size_t)(((lbase + 2) * 16 + nt) * 4) * 1024 + lane * 16;
#pragma unroll
        for (int kf = 0; kf < 8; ++kf) {
            int o = (kf >> 1) * 1024 + (kf & 1) * 8;
            uz[kf] = *(const long*)(pz + o);
            ur[kf] = *(const long*)(pr + o);
            uh[kf] = *(const long*)(ph + o);
        }
    }
    float s1r[4] = {};
    float accl = 0.f;
    int ready = 0;
    __syncthreads();
    __builtin_amdgcn_s_setprio(1);   // scan = critical chain: win SIMD arbitration

    for (int t = 0; t < tmax; ++t) {
        if constexpr (WMODE == 1) {
            if (t >= ready) {
                if (tid == 0) {
                    int vv, g = 0;
                    for (;;) {
                        vv = 1 << 30;
#pragma unroll
                        for (int q = 0; q < 4; ++q) {
                            int m = __hip_atomic_load(wflags + q, __ATOMIC_RELAXED, __HIP_MEMORY_SCOPE_AGENT);
                            vv = m < vv ? m : vv;
                        }
                        if (vv > t || ++g > (1 << 19)) break;   // fail visibly, never hang
                        __builtin_amdgcn_s_sleep(2);
                    }
                    __threadfence();          // agent acquire before data reads
                    *s_rdy = vv > t ? vv : t + 1;
                }
                __syncthreads();
                ready = *s_rdy;
            }
        } else if constexpr (WMODE == 2) {
            if (t >= ready) {
                if (tid == 0) {
                    const int ch = t >> 4;    // CHUNK == 16
                    int g = 0;
                    for (;;) {
                        int c = __hip_atomic_load(wflags + ch, __ATOMIC_RELAXED, __HIP_MEMORY_SCOPE_AGENT);
                        if (c >= 16 || ++g > (1 << 19)) break;  // fail visibly, never hang
                        __builtin_amdgcn_s_sleep(2);
                    }
                    __threadfence();          // agent acquire: inv before XP reads
                    *s_rdy = (ch + 1) * CHUNK;
                }
                __syncthreads();
                ready = *s_rdy;
            }
        }

        const unsigned int* xpt = xp + (size_t)(bg * 512 + t) * 3072 + lane;
        unsigned int xz = xpt[nt * 64];
        unsigned int xr = xpt[1024 + nt * 64];
        unsigned int xh = xpt[2048 + nt * 64];

        // ---- phase 1: r (on the critical path) + z-MFMAs (acc dangles) ----
        long sf[8];
#pragma unroll
        for (int kf = 0; kf < 8; ++kf) sf[kf] = *(const long*)&s1q[l15][kf * 32 + quad * 8];
        floatx4 za = {0.f, 0.f, 0.f, 0.f}, ra = za;
#pragma unroll
        for (int kf = 0; kf < 8; ++kf) {
            ra = MFMA_FP8(sf[kf], ur[kf], ra, 0, 0, 0);
            za = MFMA_FP8(sf[kf], uz[kf], za, 0, 0, 0);
        }
        float xrf[4];
        unp4(xr, xrf);
#pragma unroll
        for (int i = 0; i < 4; ++i) {
            float r = sigf(0.125f * ra[i] + 0.0625f * xrf[i]);
            rsq[rowb + i][colA] = f2q(r * s1r[i]);
        }
        BAR_LDS();   // LDS-only: XP loads / HN stores stay in flight

        // ---- phase 2: h; z-sigmoid overlaps the Uh MFMA ----
        long rf[8];
#pragma unroll
        for (int kf = 0; kf < 8; ++kf) rf[kf] = *(const long*)&rsq[l15][kf * 32 + quad * 8];
        floatx4 ha = {0.f, 0.f, 0.f, 0.f};
#pragma unroll
        for (int kf = 0; kf < 8; ++kf) ha = MFMA_FP8(rf[kf], uh[kf], ha, 0, 0, 0);
        float xzf[4], xhf[4];
        unp4(xz, xzf); unp4(xh, xhf);
#pragma unroll
        for (int i = 0; i < 4; ++i) {
            float z = sigf(0.125f * za[i] + 0.0625f * xzf[i]);
            float h = tanhfast2y(0.25f * ha[i] + 0.125f * xhf[i]);  // tanh(0.125ha+0.0625xh)
            float hn = (1.f - z) * s1r[i] + z * h;
            s1r[i] = hn;
            s1q[rowb + i][colA] = f2q(hn);
            s1o[rowb + i][colA] = hn;
        }
        BAR_LDS();   // LDS-only

        if (!SCORE) {
            // cooperative hn0 write: agent-scope relaxed stores (coherent at
            // LLC once vmcnt retires) -> POST needs no wbl2
            const int r = tid >> 6, c = (tid & 63) * 4;
            float4 f0 = *(const float4*)&s1o[r][c];
            unsigned int w0 = f2bf(f0.x) | ((unsigned)f2bf(f0.y) << 16);
            unsigned int w1 = f2bf(f0.z) | ((unsigned)f2bf(f0.w) << 16);
            unsigned int* dst = (unsigned int*)(hnout + ((size_t)(b0 + r) * 512 + t) * 256 + c);
            ast_u32(dst, w0);
            ast_u32(dst + 1, w1);
        } else if (wave == 0) {
            const int row = l15, c0 = quad * 64;
            float p = 0.f;
#pragma unroll
            for (int u = 0; u < 64; u += 4) {
                float4 sv = *(const float4*)&s1o[row][c0 + u];
                float4 wv = *(const float4*)&wo1s[c0 + u];
                p = fmaf(sv.x, wv.x, p); p = fmaf(sv.y, wv.y, p);
                p = fmaf(sv.z, wv.z, p); p = fmaf(sv.w, wv.w, p);
            }
            p += __shfl_xor(p, 16);
            p += __shfl_xor(p, 32);
            if (lane < 16 && t < lenr) {
                float sc = sigf(p);
                float d = labr - sc;
                accl = fmaf(d, d, accl);
            }
        }

        if (POST && (((t & (CHUNK - 1)) == (CHUNK - 1)) || t == tmax - 1)) {
            __syncthreads();   // vmcnt(0): all waves' agent-scope HN stores retired
            if (tid == 0)      // relaxed flag store: data already at coherent point
                __hip_atomic_store(pflag, t + 1, __ATOMIC_RELAXED, __HIP_MEMORY_SCOPE_AGENT);
        }
    }

    __builtin_amdgcn_s_setprio(0);
    if (SCORE && wave == 0) {
        accl += __shfl_xor(accl, 1);
        accl += __shfl_xor(accl, 2);
        accl += __shfl_xor(accl, 4);
        accl += __shfl_xor(accl, 8);
        if (lane == 0) atomicAdd(out, accl);
    }
}

// ---------------------------------------------------------------------------
// Fused pipeline + in-grid projA, 2072 WGs (R9 topology):
//   blocks 0-3   : layer-0 scan (waits projA counter==16 per chunk;
//                  posts flags[bg] per chunk, cheap-producer protocol)
//   blocks 4-19  : projB, 4 WGs per bg; waits flags[bg], posts flags[4+bg*4+p]
//                  (HP stores agent-scope, cheap-producer protocol)
//   blocks 20-23 : layer-1 scan + loss (waits MIN of the bg's 4 projB flags)
//   blocks 24-2071: projA, one (bg,t) each; XP agent-scope stores + counter
// ---------------------------------------------------------------------------
__global__ __launch_bounds__(1024, 4) void fused_pipeline(
    const float* __restrict__ x,
    unsigned int* __restrict__ XP, unsigned int* __restrict__ HP,
    const unsigned char* __restrict__ wpU, const unsigned char* __restrict__ wpW,
    unsigned short* __restrict__ HN,
    const int* __restrict__ xlen, const float* __restrict__ xlab,
    const float* __restrict__ Wo, float* __restrict__ out, int* flags)
{
    __shared__ __align__(16) unsigned char s1q[16][AST];
    __shared__ __align__(16) unsigned char rsq[16][AST];
    __shared__ __align__(16) float s1o[16][264];
    __shared__ float wo1s[DIM];
    __shared__ int s_rdy;

    const int bid = blockIdx.x;
    const int tid = threadIdx.x, wave = tid >> 6, lane = tid & 63;
    const int l15 = lane & 15, quad = lane >> 4;
    int* cnt = flags + 32;   // projA chunk counters, bg*32+chunk

    if (bid >= 24) {
        // ---- projA: XP[t] = x[t] @ W(l0); one (bg,t) per block ----
        const int idx = bid - 24;            // 0..2047
        const int pt = idx & 511, pbg = idx >> 9;
        const float* s = x + ((size_t)(pbg * 16 + l15) * 512 + pt) * 256;
        bf16x8 af[8];
#pragma unroll
        for (int kf = 0; kf < 8; ++kf) {
            float4 a = *(const float4*)(s + kf * 32 + quad * 8);
            float4 b = *(const float4*)(s + kf * 32 + quad * 8 + 4);
            union { unsigned short u[8]; bf16x8 v; } cv;
            cv.u[0] = f2bf(a.x); cv.u[1] = f2bf(a.y); cv.u[2] = f2bf(a.z); cv.u[3] = f2bf(a.w);
            cv.u[4] = f2bf(b.x); cv.u[5] = f2bf(b.y); cv.u[6] = f2bf(b.z); cv.u[7] = f2bf(b.w);
            af[kf] = cv.v;
        }
        floatx4 az = {0.f, 0.f, 0.f, 0.f}, ar = az, ah = az;
        const unsigned char* bz = wpW + (size_t)((0 * 16 + wave) * 8) * 1024 + lane * 16;
        const unsigned char* br = wpW + (size_t)((1 * 16 + wave) * 8) * 1024 + lane * 16;
        const unsigned char* bh = wpW + (size_t)((2 * 16 + wave) * 8) * 1024 + lane * 16;
#pragma unroll
        for (int kf = 0; kf < 8; ++kf) {
            az = MFMA_BF16(af[kf], *(const bf16x8*)(bz + kf * 1024), az, 0, 0, 0);
            ar = MFMA_BF16(af[kf], *(const bf16x8*)(br + kf * 1024), ar, 0, 0, 0);
            ah = MFMA_BF16(af[kf], *(const bf16x8*)(bh + kf * 1024), ah, 0, 0, 0);
        }
        const size_t ob = (size_t)(pbg * 512 + pt) * 3072 + wave * 64 + lane;
        ast_u32(&XP[ob],        pk2(16.f * az[0], 16.f * az[1]) | (pk2(16.f * az[2], 16.f * az[3]) << 16));
        ast_u32(&XP[ob + 1024], pk2(16.f * ar[0], 16.f * ar[1]) | (pk2(16.f * ar[2], 16.f * ar[3]) << 16));
        ast_u32(&XP[ob + 2048], pk2(16.f * ah[0], 16.f * ah[1]) | (pk2(16.f * ah[2], 16.f * ah[3]) << 16));
        __syncthreads();   // vmcnt(0): all block's coherent stores complete
        if (tid == 0)
            __hip_atomic_fetch_add(cnt + pbg * 32 + (pt >> 4), 1,
                                   __ATOMIC_RELAXED, __HIP_MEMORY_SCOPE_AGENT);
        return;
    }

    int role, bg, p = 0;
    if (bid < 4)       { role = 0; bg = bid; }
    else if (bid < 20) { role = 1; bg = (bid - 4) >> 2; p = (bid - 4) & 3; }
    else               { role = 2; bg = bid - 20; }
    const int b0 = bg * 16;

    // uniform tmax = max xlen over this bg's 16 rows (same in all stages)
    int v = xlen[b0 + l15];
#pragma unroll
    for (int o = 1; o < 16; o <<= 1) v = max(v, __shfl_xor(v, o));
    const int tmax = __builtin_amdgcn_readfirstlane(v);

    if (role == 0) {
        scan_body<0, 2, 1>(XP, wpU, 0, bg, HN, xlen, xlab, Wo, out,
                           cnt + bg * 32, flags + bg, s1q, rsq, s1o, wo1s, &s_rdy, tmax);
    } else if (role == 2) {
        scan_body<1, 1, 0>(HP, wpU, 3, bg, nullptr, xlen, xlab, Wo, out,
                           flags + 4 + bg * 4, nullptr, s1q, rsq, s1o, wo1s, &s_rdy, tmax);
    } else {
        // ---- projB: HP[t] = HN[t] @ W(l1); this WG owns 4 t per chunk ----
        int* wf = flags + bg;
        int* pf = flags + 4 + bg * 4 + p;
        const unsigned char* bz = wpW + (size_t)(((3 + 0) * 16 + wave) * 8) * 1024 + lane * 16;
        const unsigned char* br = wpW + (size_t)(((3 + 1) * 16 + wave) * 8) * 1024 + lane * 16;
        const unsigned char* bh = wpW + (size_t)(((3 + 2) * 16 + wave) * 8) * 1024 + lane * 16;
        for (int base = 0; base < tmax; base += CHUNK) {
            const int target = (base + CHUNK < tmax) ? base + CHUNK : tmax;
            if (tid == 0) {
                int vv, g = 0;
                for (;;) {
                    vv = __hip_atomic_load(wf, __ATOMIC_RELAXED, __HIP_MEMORY_SCOPE_AGENT);
                    if (vv >= target || ++g > (1 << 19)) break;
                    __builtin_amdgcn_s_sleep(2);
                }
                __threadfence();   // acquire: inv before reading scan0's HN chunk
            }
            __syncthreads();       // no wave reads HN before the inv

            const int t0 = base + p * 4;
            const int t1 = (t0 + 4 < tmax) ? t0 + 4 : tmax;
            for (int t = t0; t < t1; ++t) {
                const unsigned short* sA = HN + ((size_t)(b0 + l15) * 512 + t) * 256;
                bf16x8 af[8];
#pragma unroll
                for (int kf = 0; kf < 8; ++kf) af[kf] = *(const bf16x8*)(sA + kf * 32 + quad * 8);
                floatx4 az = {0.f, 0.f, 0.f, 0.f}, ar = az, ah = az;
#pragma unroll
                for (int kf = 0; kf < 8; ++kf) {
                    az = MFMA_BF16(af[kf], *(const bf16x8*)(bz + kf * 1024), az, 0, 0, 0);
                    ar = MFMA_BF16(af[kf], *(const bf16x8*)(br + kf * 1024), ar, 0, 0, 0);
                    ah = MFMA_BF16(af[kf], *(const bf16x8*)(bh + kf * 1024), ah, 0, 0, 0);
                }
                const size_t ob = (size_t)(bg * 512 + t) * 3072 + wave * 64 + lane;
                ast_u32(&HP[ob],        pk2(16.f * az[0], 16.f * az[1]) | (pk2(16.f * az[2], 16.f * az[3]) << 16));
                ast_u32(&HP[ob + 1024], pk2(16.f * ar[0], 16.f * ar[1]) | (pk2(16.f * ar[2], 16.f * ar[3]) << 16));
                ast_u32(&HP[ob + 2048], pk2(16.f * ah[0], 16.f * ah[1]) | (pk2(16.f * ah[2], 16.f * ah[3]) << 16));
            }

            __syncthreads();   // vmcnt(0): all waves' agent-scope HP stores retired
            if (tid == 0)      // relaxed flag: data already at coherent point
                __hip_atomic_store(pf, base + CHUNK, __ATOMIC_RELAXED, __HIP_MEMORY_SCOPE_AGENT);
        }
    }
}

extern "C" void kernel_launch(void* const* d_in, const int* in_sizes, int n_in,
                              void* d_out, int out_size, void* d_ws, size_t ws_size,
                              hipStream_t stream) {
    const float* x    = (const float*)d_in[0];
    const int*   xlen = (const int*)d_in[1];
    const float* xlab = (const float*)d_in[2];
    const float* Wz   = (const float*)d_in[3];
    const float* Uz   = (const float*)d_in[4];
    const float* Wr   = (const float*)d_in[5];
    const float* Ur   = (const float*)d_in[6];
    const float* Wh   = (const float*)d_in[7];
    const float* Uh   = (const float*)d_in[8];
    const float* Wo   = (const float*)d_in[9];
    float* out = (float*)d_out;

    unsigned char* ws  = (unsigned char*)d_ws;
    unsigned char* wpU = ws;                                 // fp8 U-frags, 384 KB
    unsigned char* wpW = ws + OFF_WPW;                       // bf16 W-frags, 768 KB
    int*           FLG = (int*)(ws + OFF_FLG);               // flags + counters
    unsigned int*  XP  = (unsigned int*)(ws + OFF_XP);       // 25.2 MB
    unsigned int*  HP  = (unsigned int*)(ws + OFF_HP);       // 25.2 MB
    unsigned short* HN = (unsigned short*)(ws + OFF_HN);     // 16.8 MB

    // ws re-poisoned every call -> rebuild everything (incl. flags) each time.
    prep_weights<<<1536, 256, 0, stream>>>(Wz, Wr, Wh, Uz, Ur, Uh, ws, out);
    fused_pipeline<<<2072, 1024, 0, stream>>>(x, XP, HP, wpU, wpW, HN,
                                              xlen, xlab, Wo, out, FLG);
}